// Round 2
// baseline (438.196 us; speedup 1.0000x reference)
//
#include <hip/hip_runtime.h>
#include <stdint.h>

#define M_DIM 8192   // BATCH*SEQ = 4*2048
#define N_DIM 4096
#define K_DIM 4096
#define BM 128
#define BN 128
#define BK 64

typedef int v4i __attribute__((ext_vector_type(4)));
typedef int v16i __attribute__((ext_vector_type(16)));
typedef unsigned u32;

__device__ __forceinline__ void gll16(const void* g, void* l) {
  __builtin_amdgcn_global_load_lds(
      (const __attribute__((address_space(1))) void*)g,
      (__attribute__((address_space(3))) void*)l, 16, 0, 0);
}

__device__ __forceinline__ u32 pack4(const int4 v) {
  return (v.x & 0xffu) | ((v.y & 0xffu) << 8) | ((v.z & 0xffu) << 16) |
         ((u32)(v.w & 0xffu) << 24);
}

// ---------------------------------------------------------------------------
// Header-based dtype detection: first 4 KB of X is in-bounds under both
// hypotheses; i32 materialization iff every word is a sign-extended int8.
// Block-local consensus (all blocks compute the same answer).
// ---------------------------------------------------------------------------
__device__ __forceinline__ bool hdr_is_i32(const int* __restrict__ X, int tid,
                                           int* ok) {
  if (tid == 0) *ok = 1;
  __syncthreads();
  int good = 1;
  for (int i = tid; i < 1024; i += 256) {
    const int w = X[i];
    good &= (w == (int)(int8_t)(w & 0xff));
  }
  if (!good) atomicAnd(ok, 0);
  __syncthreads();
  return *ok != 0;
}

// Standalone detect (fallback paths only; writes flag for gemm_inA).
__global__ __launch_bounds__(256) void detect_i32(const int* __restrict__ X,
                                                  u32* __restrict__ flag) {
  __shared__ int ok;
  const bool i32 = hdr_is_i32(X, threadIdx.x, &ok);
  if (threadIdx.x == 0) *flag = i32 ? 1u : 0u;
}

// ---------------------------------------------------------------------------
// pack_x_f: X -> packed int8 bytes; dtype self-detected from header.
// ---------------------------------------------------------------------------
__global__ __launch_bounds__(256) void pack_x_f(const void* __restrict__ Xin,
                                                u32* __restrict__ out) {
  __shared__ int ok;
  const bool i32 = hdr_is_i32((const int*)Xin, threadIdx.x, &ok);
  const int base = blockIdx.x * 1024 + threadIdx.x;
  if (i32) {
    const int4* in = (const int4*)Xin;  // 128 MB source (valid when int32)
#pragma unroll
    for (int j = 0; j < 4; ++j) {
      const int idx = base + j * 256;
      out[idx] = pack4(in[idx]);
    }
  } else {
    const u32* in = (const u32*)Xin;    // 32 MB source (already bytes)
#pragma unroll
    for (int j = 0; j < 4; ++j) {
      const int idx = base + j * 256;
      out[idx] = in[idx];
    }
  }
}

// ---------------------------------------------------------------------------
// packT_w_f: W [K][N] -> WT int8 [N][K], 64x64 tiles; dtype from X header
// (X and W share the same materialization).
// ---------------------------------------------------------------------------
__global__ __launch_bounds__(256) void packT_w_f(const void* __restrict__ Wv,
                                                 int8_t* __restrict__ WT,
                                                 const int* __restrict__ Xhdr) {
  __shared__ u32 lds[64 * 21];
  __shared__ int ok;
  const int tid = threadIdx.x;
  const bool i32 = hdr_is_i32(Xhdr, tid, &ok);
  const int tk = blockIdx.x & 63;   // k-tile
  const int tn = blockIdx.x >> 6;   // n-tile
  const int k0 = tk * 64, n0 = tn * 64;

#pragma unroll
  for (int j = 0; j < 4; ++j) {
    const int id = j * 256 + tid;
    const int k = id >> 4, c = id & 15;
    u32 word;
    if (i32) {
      const int4 v =
          *(const int4*)((const int*)Wv + (size_t)(k0 + k) * N_DIM + n0 + c * 4);
      word = pack4(v);
    } else {
      word = *(const u32*)((const int8_t*)Wv + (size_t)(k0 + k) * N_DIM + n0 +
                           c * 4);
    }
    lds[k * 21 + c] = word;  // bytes of W[k0+k][n0+c*4 .. +4]
  }
  __syncthreads();
  const int kd = tid & 15, nq = tid >> 4;
  const u32 d0 = lds[(kd * 4 + 0) * 21 + nq];
  const u32 d1 = lds[(kd * 4 + 1) * 21 + nq];
  const u32 d2 = lds[(kd * 4 + 2) * 21 + nq];
  const u32 d3 = lds[(kd * 4 + 3) * 21 + nq];
  u32* outp = (u32*)WT;
#pragma unroll
  for (int i = 0; i < 4; ++i) {
    const u32 e = ((d0 >> (8 * i)) & 0xffu) | (((d1 >> (8 * i)) & 0xffu) << 8) |
                  (((d2 >> (8 * i)) & 0xffu) << 16) |
                  (((d3 >> (8 * i)) & 0xffu) << 24);
    const int n = n0 + nq * 4 + i;
    outp[(size_t)n * (K_DIM / 4) + (k0 / 4) + kd] = e;
  }
}

// ---------------------------------------------------------------------------
// epilogue (128² fallback): C/D layout col = lane&15, row = quad*4 + reg.
// ---------------------------------------------------------------------------
__device__ __forceinline__ void epilogue(const v4i acc[4][4], float a,
                                         const float* __restrict__ bScale,
                                         int* __restrict__ Y, int bm, int bn,
                                         int wm, int wn, int quad, int l16) {
  const int nBase = bn * BN + wn * 64 + l16;
  float bs[4];
#pragma unroll
  for (int ni = 0; ni < 4; ++ni) bs[ni] = bScale[nBase + ni * 16];
#pragma unroll
  for (int mi = 0; mi < 4; ++mi) {
    const int m0 = bm * BM + wm * 64 + mi * 16 + quad * 4;
#pragma unroll
    for (int r = 0; r < 4; ++r) {
      int* row = Y + (size_t)(m0 + r) * N_DIM + nBase;
#pragma unroll
      for (int ni = 0; ni < 4; ++ni) {
        float v = ((float)acc[mi][ni][r] * a) * bs[ni];
        v = rintf(v);
        v = fminf(fmaxf(v, -128.f), 127.f);
        row[ni * 16] = (int)v;
      }
    }
  }
}

// ---------------------------------------------------------------------------
// gemm_256: 256x256 tile, 8 waves (2M x 4N), 8-phase schedule with
// mfma_i32_32x32x32_i8 (4404 TOPS ceiling, 8 MFMA/phase):
//  - K as 64 ksteps of 64 B; LDS ring of 4 kstep-slots/operand (128 KB).
//  - prefetch depth 3; steady-state wait = vmcnt(8), tail 8->4->0 (T3+T4).
//  - T2 XOR swizzle (16B chunk ^= (row>>1)&3) via pre-swizzled global source
//    + swizzled ds_read (global_load_lds writes linearly). Read-side
//    selector is lane-constant: sw = ((lane&31)>>1)&3.
//  - A frag: row = lane&31, k = (lane>>5)*16 + byte (kh selects chunk ^2).
//  - C/D:    col = lane&31, row = (reg&3) + 8*(reg>>2) + 4*(lane>>5).
//  - T5 setprio around MFMA clusters; T1 bijective XCD swizzle (512%8==0).
// ---------------------------------------------------------------------------
__global__ __launch_bounds__(512, 2) void gemm_256(
    const int8_t* __restrict__ X, const int8_t* __restrict__ WT,
    const float* __restrict__ aScale, const float* __restrict__ bScale,
    int* __restrict__ Y) {
  __shared__ __align__(16) int8_t lds[131072];  // A ring 64KB | B ring 64KB
  const int tid = threadIdx.x;
  const int lane = tid & 63;
  const int wave = tid >> 6;
  const int l31 = lane & 31, h = lane >> 5;
  const int wm = wave >> 2, wn = wave & 3;  // 2 x 4 wave grid

  // XCD-aware bijective swizzle: nwg=512, 64 blocks/XCD
  const int swzb = (blockIdx.x & 7) * 64 + (blockIdx.x >> 3);
  const int bn = swzb & 15, bm = swzb >> 4;  // bn inner: A-panel reuse per XCD

  // write-side swizzle: row = tid>>2 -> (row>>1)&3 = (tid>>3)&3
  const int clog = (((tid & 3) ^ ((tid >> 3) & 3)) << 4);
  // read-side selector (lane-constant; mi*32/ni*32/wm*128/wn*64 are 0 mod 8 rows)
  const int sw = (l31 >> 1) & 3;
  const int pc0 = (h ^ sw) << 4;        // kh=0 chunk byte offset
  const int pc1 = pc0 ^ 32;             // kh=1 chunk byte offset

  const int8_t* xa = X + (size_t)(bm * 256 + (tid >> 2)) * K_DIM + clog;
  const int8_t* xb = WT + (size_t)(bn * 256 + (tid >> 2)) * K_DIM + clog;
  int8_t* ldsA = lds + tid * 16;           // linear DMA dest, round1 at +8192
  int8_t* ldsB = lds + 65536 + tid * 16;
  const int8_t* aB0 = lds + (wm * 128 + l31) * 64 + pc0;
  const int8_t* aB1 = lds + (wm * 128 + l31) * 64 + pc1;
  const int8_t* bB0 = lds + 65536 + (wn * 64 + l31) * 64 + pc0;
  const int8_t* bB1 = lds + 65536 + (wn * 64 + l31) * 64 + pc1;

  v16i acc[4][2] = {};

  // prologue: stage ksteps 0..2 (per kstep: A r0, A r1, B r0, B r1)
#pragma unroll
  for (int t = 0; t < 3; ++t) {
    gll16(xa + t * 64, ldsA + t * 16384);
    gll16(xa + (size_t)128 * K_DIM + t * 64, ldsA + t * 16384 + 8192);
    gll16(xb + t * 64, ldsB + t * 16384);
    gll16(xb + (size_t)128 * K_DIM + t * 64, ldsB + t * 16384 + 8192);
  }
  asm volatile("s_waitcnt vmcnt(8)" ::: "memory");  // kstep0 landed; 1,2 in flight
  __builtin_amdgcn_s_barrier();

  for (int g = 0; g < 64; ++g) {
    const int soff = (g & 3) << 14;
    const int poff = ((g + 3) & 3) << 14;
    const bool pre = g <= 60;
    v4i af[4], bf[2];
    // ---- phase 0: kh=0 (8 MFMA), stage A rounds of kstep g+3 ----
#pragma unroll
    for (int mi = 0; mi < 4; ++mi)
      af[mi] = *(const v4i*)(aB0 + soff + mi * 2048);
#pragma unroll
    for (int ni = 0; ni < 2; ++ni)
      bf[ni] = *(const v4i*)(bB0 + soff + ni * 2048);
    if (pre) {
      const int8_t* s = xa + (size_t)(g + 3) * 64;
      gll16(s, ldsA + poff);
      gll16(s + (size_t)128 * K_DIM, ldsA + poff + 8192);
    }
    __builtin_amdgcn_s_barrier();
    asm volatile("s_waitcnt lgkmcnt(0)" ::: "memory");
    __builtin_amdgcn_sched_barrier(0);
    __builtin_amdgcn_s_setprio(1);
#pragma unroll
    for (int mi = 0; mi < 4; ++mi)
#pragma unroll
      for (int ni = 0; ni < 2; ++ni)
        acc[mi][ni] = __builtin_amdgcn_mfma_i32_32x32x32_i8(
            af[mi], bf[ni], acc[mi][ni], 0, 0, 0);
    __builtin_amdgcn_s_setprio(0);
    __builtin_amdgcn_s_barrier();

    // ---- phase 1: kh=1 (8 MFMA), stage B rounds of kstep g+3 ----
#pragma unroll
    for (int mi = 0; mi < 4; ++mi)
      af[mi] = *(const v4i*)(aB1 + soff + mi * 2048);
#pragma unroll
    for (int ni = 0; ni < 2; ++ni)
      bf[ni] = *(const v4i*)(bB1 + soff + ni * 2048);
    if (pre) {
      const int8_t* s = xb + (size_t)(g + 3) * 64;
      gll16(s, ldsB + poff);
      gll16(s + (size_t)128 * K_DIM, ldsB + poff + 8192);
    }
    __builtin_amdgcn_s_barrier();
    asm volatile("s_waitcnt lgkmcnt(0)" ::: "memory");
    __builtin_amdgcn_sched_barrier(0);
    __builtin_amdgcn_s_setprio(1);
#pragma unroll
    for (int mi = 0; mi < 4; ++mi)
#pragma unroll
      for (int ni = 0; ni < 2; ++ni)
        acc[mi][ni] = __builtin_amdgcn_mfma_i32_32x32x32_i8(
            af[mi], bf[ni], acc[mi][ni], 0, 0, 0);
    __builtin_amdgcn_s_setprio(0);
    // counted retire: keep 2 future ksteps in flight (never drain to 0
    // until the tail)
    if (g < 61)
      asm volatile("s_waitcnt vmcnt(8)" ::: "memory");
    else if (g == 61)
      asm volatile("s_waitcnt vmcnt(4)" ::: "memory");
    else
      asm volatile("s_waitcnt vmcnt(0)" ::: "memory");
    __builtin_amdgcn_s_barrier();
  }

  // ---- epilogue: col = lane&31, row = (reg&3) + 8*(reg>>2) + 4*h ----
  const float a = aScale[0];
  const int nB = bn * 256 + wn * 64 + l31;
  const float bs0 = bScale[nB];
  const float bs1 = bScale[nB + 32];
#pragma unroll
  for (int mi = 0; mi < 4; ++mi) {
#pragma unroll
    for (int ni = 0; ni < 2; ++ni) {
      const float bsv = ni ? bs1 : bs0;
      const int nCol = nB + ni * 32;
#pragma unroll
      for (int r = 0; r < 16; ++r) {
        const int row =
            bm * 256 + wm * 128 + mi * 32 + (r & 3) + 8 * (r >> 2) + 4 * h;
        float v = ((float)acc[mi][ni][r] * a) * bsv;
        v = rintf(v);
        v = fminf(fmaxf(v, -128.f), 127.f);
        Y[(size_t)row * N_DIM + nCol] = (int)v;
      }
    }
  }
}

// ---------------------------------------------------------------------------
// gemm_inA (fallback when ws only fits WT): A read from X (dtype by flag,
// packed in-kernel), B from packed WT. GEMM never writes ws -> no race.
// ---------------------------------------------------------------------------
__global__ __launch_bounds__(256) void gemm_inA(
    const void* __restrict__ Xv, const int8_t* __restrict__ WT,
    const float* __restrict__ aScale, const float* __restrict__ bScale,
    int* __restrict__ Y, const u32* __restrict__ flag) {
  __shared__ __align__(16) int8_t As[BM * BK];
  __shared__ __align__(16) int8_t Bs[BN * BK];
  const bool i32 = (*flag != 0);
  const int tid = threadIdx.x;
  const int lane = tid & 63, wave = tid >> 6;
  const int quad = lane >> 4, l16 = lane & 15;
  const int wm = wave & 1, wn = wave >> 1;
  const int bn = blockIdx.x & 31;
  const int bm = blockIdx.x >> 5;

  const int r0 = tid >> 2;
  const int c0 = (tid & 3) * 16;   // k offset (elements) within BK
  const int8_t* Bg0 = WT + (size_t)(bn * BN + r0) * K_DIM + c0;
  const int8_t* Bg1 = Bg0 + (size_t)64 * K_DIM;
  int8_t* Al0 = As + tid * 16;
  int8_t* Al1 = Al0 + 4096;
  int8_t* Bl0 = Bs + tid * 16;
  int8_t* Bl1 = Bl0 + 4096;

  v4i acc[4][4] = {};
  const int8_t* aLds = As + (wm * 64 + l16) * BK + quad * 16;
  const int8_t* bLds = Bs + (wn * 64 + l16) * BK + quad * 16;

  if (i32) {
    const int* Xg0 = (const int*)Xv + (size_t)(bm * BM + r0) * K_DIM + c0;
    const int* Xg1 = Xg0 + (size_t)64 * K_DIM;
    for (int k0 = 0; k0 < K_DIM; k0 += BK) {
      gll16(Bg0 + k0, Bl0);
      gll16(Bg1 + k0, Bl1);
      const int4* p0 = (const int4*)(Xg0 + k0);
      const int4* p1 = (const int4*)(Xg1 + k0);
      uint4 w0, w1;
      w0.x = pack4(p0[0]); w0.y = pack4(p0[1]);
      w0.z = pack4(p0[2]); w0.w = pack4(p0[3]);
      w1.x = pack4(p1[0]); w1.y = pack4(p1[1]);
      w1.z = pack4(p1[2]); w1.w = pack4(p1[3]);
      *(uint4*)Al0 = w0;
      *(uint4*)Al1 = w1;
      __syncthreads();
      v4i af[4], bf[4];
#pragma unroll
      for (int i = 0; i < 4; ++i) af[i] = *(const v4i*)(aLds + i * 16 * BK);
#pragma unroll
      for (int i = 0; i < 4; ++i) bf[i] = *(const v4i*)(bLds + i * 16 * BK);
#pragma unroll
      for (int mi = 0; mi < 4; ++mi)
#pragma unroll
        for (int ni = 0; ni < 4; ++ni)
          acc[mi][ni] = __builtin_amdgcn_mfma_i32_16x16x64_i8(
              af[mi], bf[ni], acc[mi][ni], 0, 0, 0);
      __syncthreads();
    }
  } else {
    const int8_t* Ag0 = (const int8_t*)Xv + (size_t)(bm * BM + r0) * K_DIM + c0;
    const int8_t* Ag1 = Ag0 + (size_t)64 * K_DIM;
    for (int k0 = 0; k0 < K_DIM; k0 += BK) {
      gll16(Ag0 + k0, Al0);
      gll16(Ag1 + k0, Al1);
      gll16(Bg0 + k0, Bl0);
      gll16(Bg1 + k0, Bl1);
      __syncthreads();
      v4i af[4], bf[4];
#pragma unroll
      for (int i = 0; i < 4; ++i) af[i] = *(const v4i*)(aLds + i * 16 * BK);
#pragma unroll
      for (int i = 0; i < 4; ++i) bf[i] = *(const v4i*)(bLds + i * 16 * BK);
#pragma unroll
      for (int mi = 0; mi < 4; ++mi)
#pragma unroll
        for (int ni = 0; ni < 4; ++ni)
          acc[mi][ni] = __builtin_amdgcn_mfma_i32_16x16x64_i8(
              af[mi], bf[ni], acc[mi][ni], 0, 0, 0);
      __syncthreads();
    }
  }
  epilogue(acc, aScale[0], bScale, Y, bm, bn, wm, wn, quad, l16);
}

extern "C" void kernel_launch(void* const* d_in, const int* in_sizes, int n_in,
                              void* d_out, int out_size, void* d_ws,
                              size_t ws_size, hipStream_t stream) {
  const void* Xv = d_in[0];
  const void* Wv = d_in[1];
  const float* a = (const float*)d_in[2];
  const float* b = (const float*)d_in[3];
  int* Y = (int*)d_out;

  const size_t xB = (size_t)M_DIM * K_DIM;  // 32 MB packed X
  const size_t wB = (size_t)N_DIM * K_DIM;  // 16 MB packed W^T

  if (ws_size >= xB + wB + 64) {
    int8_t* Xp = (int8_t*)d_ws;
    int8_t* WT = (int8_t*)d_ws + xB;
    pack_x_f<<<(M_DIM * K_DIM / 4) / 1024, 256, 0, stream>>>(Xv, (u32*)Xp);
    packT_w_f<<<(K_DIM / 64) * (N_DIM / 64), 256, 0, stream>>>(Wv, WT,
                                                               (const int*)Xv);
    gemm_256<<<(M_DIM / 256) * (N_DIM / 256), 512, 0, stream>>>(Xp, WT, a, b,
                                                                Y);
  } else if (ws_size >= wB + 64) {
    int8_t* WT = (int8_t*)d_ws;
    u32* flag = (u32*)((int8_t*)d_ws + wB);
    detect_i32<<<1, 256, 0, stream>>>((const int*)Xv, flag);
    packT_w_f<<<(K_DIM / 64) * (N_DIM / 64), 256, 0, stream>>>(Wv, WT,
                                                               (const int*)Xv);
    gemm_inA<<<(M_DIM / BM) * (N_DIM / BN), 256, 0, stream>>>(Xv, WT, a, b, Y,
                                                              flag);
  } else {
    int8_t* WT = (int8_t*)d_ws;
    u32* flag = (u32*)((int8_t*)d_ws + (ws_size >= wB + 4 ? wB : 0));
    detect_i32<<<1, 256, 0, stream>>>((const int*)Xv, flag);
    packT_w_f<<<(K_DIM / 64) * (N_DIM / 64), 256, 0, stream>>>(Wv, WT,
                                                               (const int*)Xv);
    gemm_inA<<<(M_DIM / BM) * (N_DIM / BN), 256, 0, stream>>>(Xv, WT, a, b, Y,
                                                              flag);
  }
}

// Round 3
// 407.054 us; speedup vs baseline: 1.0765x; 1.0765x over previous
//
#include <hip/hip_runtime.h>
#include <stdint.h>

#define M_DIM 8192   // BATCH*SEQ = 4*2048
#define N_DIM 4096
#define K_DIM 4096
#define BM 128
#define BN 128
#define BK 64

typedef int v4i __attribute__((ext_vector_type(4)));
typedef unsigned u32;

__device__ __forceinline__ void gll16(const void* g, void* l) {
  __builtin_amdgcn_global_load_lds(
      (const __attribute__((address_space(1))) void*)g,
      (__attribute__((address_space(3))) void*)l, 16, 0, 0);
}

__device__ __forceinline__ u32 pack4(const int4 v) {
  return (v.x & 0xffu) | ((v.y & 0xffu) << 8) | ((v.z & 0xffu) << 16) |
         ((u32)(v.w & 0xffu) << 24);
}

// ---------------------------------------------------------------------------
// Header-based dtype detection: first 4 KB of X is in-bounds under both
// hypotheses; i32 materialization iff every word is a sign-extended int8.
// ---------------------------------------------------------------------------
__device__ __forceinline__ bool hdr_is_i32(const int* __restrict__ X, int tid,
                                           int* ok) {
  if (tid == 0) *ok = 1;
  __syncthreads();
  int good = 1;
  for (int i = tid; i < 1024; i += 256) {
    const int w = X[i];
    good &= (w == (int)(int8_t)(w & 0xff));
  }
  if (!good) atomicAnd(ok, 0);
  __syncthreads();
  return *ok != 0;
}

// Standalone detect (fallback paths only; writes flag for gemm_inA).
__global__ __launch_bounds__(256) void detect_i32(const int* __restrict__ X,
                                                  u32* __restrict__ flag) {
  __shared__ int ok;
  const bool i32 = hdr_is_i32(X, threadIdx.x, &ok);
  if (threadIdx.x == 0) *flag = i32 ? 1u : 0u;
}

// ---------------------------------------------------------------------------
// pack_x_f: X -> packed int8 bytes; dtype self-detected from header.
// ---------------------------------------------------------------------------
__global__ __launch_bounds__(256) void pack_x_f(const void* __restrict__ Xin,
                                                u32* __restrict__ out) {
  __shared__ int ok;
  const bool i32 = hdr_is_i32((const int*)Xin, threadIdx.x, &ok);
  const int base = blockIdx.x * 1024 + threadIdx.x;
  if (i32) {
    const int4* in = (const int4*)Xin;  // 128 MB source (valid when int32)
#pragma unroll
    for (int j = 0; j < 4; ++j) {
      const int idx = base + j * 256;
      out[idx] = pack4(in[idx]);
    }
  } else {
    const u32* in = (const u32*)Xin;    // 32 MB source (already bytes)
#pragma unroll
    for (int j = 0; j < 4; ++j) {
      const int idx = base + j * 256;
      out[idx] = in[idx];
    }
  }
}

// ---------------------------------------------------------------------------
// packT_w_f: W [K][N] -> WT int8 [N][K], 64x64 tiles; dtype from X header
// (X and W share the same materialization).
// ---------------------------------------------------------------------------
__global__ __launch_bounds__(256) void packT_w_f(const void* __restrict__ Wv,
                                                 int8_t* __restrict__ WT,
                                                 const int* __restrict__ Xhdr) {
  __shared__ u32 lds[64 * 21];
  __shared__ int ok;
  const int tid = threadIdx.x;
  const bool i32 = hdr_is_i32(Xhdr, tid, &ok);
  const int tk = blockIdx.x & 63;   // k-tile
  const int tn = blockIdx.x >> 6;   // n-tile
  const int k0 = tk * 64, n0 = tn * 64;

#pragma unroll
  for (int j = 0; j < 4; ++j) {
    const int id = j * 256 + tid;
    const int k = id >> 4, c = id & 15;
    u32 word;
    if (i32) {
      const int4 v =
          *(const int4*)((const int*)Wv + (size_t)(k0 + k) * N_DIM + n0 + c * 4);
      word = pack4(v);
    } else {
      word = *(const u32*)((const int8_t*)Wv + (size_t)(k0 + k) * N_DIM + n0 +
                           c * 4);
    }
    lds[k * 21 + c] = word;  // bytes of W[k0+k][n0+c*4 .. +4]
  }
  __syncthreads();
  const int kd = tid & 15, nq = tid >> 4;
  const u32 d0 = lds[(kd * 4 + 0) * 21 + nq];
  const u32 d1 = lds[(kd * 4 + 1) * 21 + nq];
  const u32 d2 = lds[(kd * 4 + 2) * 21 + nq];
  const u32 d3 = lds[(kd * 4 + 3) * 21 + nq];
  u32* outp = (u32*)WT;
#pragma unroll
  for (int i = 0; i < 4; ++i) {
    const u32 e = ((d0 >> (8 * i)) & 0xffu) | (((d1 >> (8 * i)) & 0xffu) << 8) |
                  (((d2 >> (8 * i)) & 0xffu) << 16) |
                  (((d3 >> (8 * i)) & 0xffu) << 24);
    const int n = n0 + nq * 4 + i;
    outp[(size_t)n * (K_DIM / 4) + (k0 / 4) + kd] = e;
  }
}

// ---------------------------------------------------------------------------
// epilogue (128² fallback): C/D layout col = lane&15, row = quad*4 + reg.
// ---------------------------------------------------------------------------
__device__ __forceinline__ void epilogue(const v4i acc[4][4], float a,
                                         const float* __restrict__ bScale,
                                         int* __restrict__ Y, int bm, int bn,
                                         int wm, int wn, int quad, int l16) {
  const int nBase = bn * BN + wn * 64 + l16;
  float bs[4];
#pragma unroll
  for (int ni = 0; ni < 4; ++ni) bs[ni] = bScale[nBase + ni * 16];
#pragma unroll
  for (int mi = 0; mi < 4; ++mi) {
    const int m0 = bm * BM + wm * 64 + mi * 16 + quad * 4;
#pragma unroll
    for (int r = 0; r < 4; ++r) {
      int* row = Y + (size_t)(m0 + r) * N_DIM + nBase;
#pragma unroll
      for (int ni = 0; ni < 4; ++ni) {
        float v = ((float)acc[mi][ni][r] * a) * bs[ni];
        v = rintf(v);
        v = fminf(fmaxf(v, -128.f), 127.f);
        row[ni * 16] = (int)v;
      }
    }
  }
}

// ---------------------------------------------------------------------------
// gemm_256: 256x256 tile, 8 waves (2M x 4N), mfma_i32_16x16x64_i8 (the
// HW-verified conflict-free fragment layout from R1), ONE barrier per kstep:
//  - K as 64 ksteps of 64 B; LDS ring of 4 kstep-slots/operand (128 KB).
//  - prefetch distance 3: at kstep g stage slot (g+3)&3 == (g-1)&3, which is
//    ring-safe with a single end-of-kstep barrier (wave skew < 1 kstep, so
//    concurrent readers are in slots g / g+1 only).
//  - counted vmcnt(8) before the barrier retires kstep g+1's DMA writes
//    in every wave; the barrier publishes them (T3+T4, never drain to 0).
//  - NO forced lgkmcnt(0) / sched_barrier: compiler emits fine-grained
//    lgkmcnt per-MFMA, so ds_read latency hides under the MFMA cluster.
//  - T2 XOR swizzle (16B chunk ^= (row>>1)&3) via pre-swizzled global source
//    + swizzled ds_read address (global_load_lds writes linearly).
//  - T5 setprio around the MFMA region; T1 bijective XCD swizzle (512%8==0).
// ---------------------------------------------------------------------------
__global__ __launch_bounds__(512, 2) void gemm_256(
    const int8_t* __restrict__ X, const int8_t* __restrict__ WT,
    const float* __restrict__ aScale, const float* __restrict__ bScale,
    int* __restrict__ Y) {
  __shared__ __align__(16) int8_t lds[131072];  // A ring 64KB | B ring 64KB
  const int tid = threadIdx.x;
  const int lane = tid & 63;
  const int wave = tid >> 6;
  const int quad = lane >> 4, l16 = lane & 15;
  const int wm = wave >> 2, wn = wave & 3;  // 2 x 4 wave grid

  // XCD-aware bijective swizzle: nwg=512, 64 blocks/XCD
  const int swzb = (blockIdx.x & 7) * 64 + (blockIdx.x >> 3);
  const int bn = swzb & 15, bm = swzb >> 4;  // bn inner: A-panel reuse per XCD

  // write-side swizzle selector: row = tid>>2  ->  (row>>1)&3 = (tid>>3)&3
  const int clog = (((tid & 3) ^ ((tid >> 3) & 3)) << 4);
  // read-side: row = {wm*128|wn*64} + {mi|ni}*16 + l16 -> (row>>1)&3 = (l16>>1)&3
  const int pc = quad ^ ((l16 >> 1) & 3);

  const int8_t* xa = X + (size_t)(bm * 256 + (tid >> 2)) * K_DIM + clog;
  const int8_t* xb = WT + (size_t)(bn * 256 + (tid >> 2)) * K_DIM + clog;
  int8_t* ldsA = lds + tid * 16;           // linear DMA dest, round1 at +8192
  int8_t* ldsB = lds + 65536 + tid * 16;
  const int8_t* aBase = lds + (wm * 128 + l16) * 64 + pc * 16;
  const int8_t* bBase = lds + 65536 + (wn * 64 + l16) * 64 + pc * 16;

  v4i acc[8][4] = {};

  // prologue: stage ksteps 0..2 (per kstep: A r0, A r1, B r0, B r1)
#pragma unroll
  for (int t = 0; t < 3; ++t) {
    gll16(xa + t * 64, ldsA + t * 16384);
    gll16(xa + (size_t)128 * K_DIM + t * 64, ldsA + t * 16384 + 8192);
    gll16(xb + t * 64, ldsB + t * 16384);
    gll16(xb + (size_t)128 * K_DIM + t * 64, ldsB + t * 16384 + 8192);
  }
  asm volatile("s_waitcnt vmcnt(8)" ::: "memory");  // kstep0 landed; 1,2 in flight
  __builtin_amdgcn_s_barrier();

  for (int g = 0; g < 64; ++g) {
    const int soff = (g & 3) << 14;
    const int poff = ((g + 3) & 3) << 14;
    // stage kstep g+3 (issue-only; latency hides under this kstep's MFMAs)
    if (g <= 60) {
      const int8_t* sa = xa + (size_t)(g + 3) * 64;
      const int8_t* sb = xb + (size_t)(g + 3) * 64;
      gll16(sa, ldsA + poff);
      gll16(sa + (size_t)128 * K_DIM, ldsA + poff + 8192);
      gll16(sb, ldsB + poff);
      gll16(sb + (size_t)128 * K_DIM, ldsB + poff + 8192);
    }
    // fragment reads + 32 MFMA; compiler interleaves with fine-grained lgkmcnt
    v4i bf[4], af[4], ag[4];
#pragma unroll
    for (int i = 0; i < 4; ++i) bf[i] = *(const v4i*)(bBase + soff + i * 1024);
#pragma unroll
    for (int i = 0; i < 4; ++i) af[i] = *(const v4i*)(aBase + soff + i * 1024);
    __builtin_amdgcn_s_setprio(1);
#pragma unroll
    for (int mi = 0; mi < 4; ++mi)
#pragma unroll
      for (int ni = 0; ni < 4; ++ni)
        acc[mi][ni] = __builtin_amdgcn_mfma_i32_16x16x64_i8(
            af[mi], bf[ni], acc[mi][ni], 0, 0, 0);
#pragma unroll
    for (int i = 0; i < 4; ++i)
      ag[i] = *(const v4i*)(aBase + soff + 4096 + i * 1024);
#pragma unroll
    for (int mi = 0; mi < 4; ++mi)
#pragma unroll
      for (int ni = 0; ni < 4; ++ni)
        acc[4 + mi][ni] = __builtin_amdgcn_mfma_i32_16x16x64_i8(
            ag[mi], bf[ni], acc[4 + mi][ni], 0, 0, 0);
    __builtin_amdgcn_s_setprio(0);
    // counted retire: kstep g+1 complete in this wave; barrier publishes.
    if (g <= 60)
      asm volatile("s_waitcnt vmcnt(8)" ::: "memory");
    else if (g == 61)
      asm volatile("s_waitcnt vmcnt(4)" ::: "memory");
    else
      asm volatile("s_waitcnt vmcnt(0)" ::: "memory");
    __builtin_amdgcn_s_barrier();
  }

  // ---- epilogue: col = lane&15, row = quad*4 + reg ----
  const float a = aScale[0];
  const int nBase = bn * 256 + wn * 64 + l16;
  float bs[4];
#pragma unroll
  for (int ni = 0; ni < 4; ++ni) bs[ni] = bScale[nBase + ni * 16];
#pragma unroll
  for (int mi = 0; mi < 8; ++mi) {
    const int m0 = bm * 256 + wm * 128 + mi * 16 + quad * 4;
#pragma unroll
    for (int r = 0; r < 4; ++r) {
      int* row = Y + (size_t)(m0 + r) * N_DIM + nBase;
#pragma unroll
      for (int ni = 0; ni < 4; ++ni) {
        float v = ((float)acc[mi][ni][r] * a) * bs[ni];
        v = rintf(v);
        v = fminf(fmaxf(v, -128.f), 127.f);
        row[ni * 16] = (int)v;
      }
    }
  }
}

// ---------------------------------------------------------------------------
// gemm_inA (fallback when ws only fits WT): A read from X (dtype by flag,
// packed in-kernel), B from packed WT. GEMM never writes ws -> no race.
// ---------------------------------------------------------------------------
__global__ __launch_bounds__(256) void gemm_inA(
    const void* __restrict__ Xv, const int8_t* __restrict__ WT,
    const float* __restrict__ aScale, const float* __restrict__ bScale,
    int* __restrict__ Y, const u32* __restrict__ flag) {
  __shared__ __align__(16) int8_t As[BM * BK];
  __shared__ __align__(16) int8_t Bs[BN * BK];
  const bool i32 = (*flag != 0);
  const int tid = threadIdx.x;
  const int lane = tid & 63, wave = tid >> 6;
  const int quad = lane >> 4, l16 = lane & 15;
  const int wm = wave & 1, wn = wave >> 1;
  const int bn = blockIdx.x & 31;
  const int bm = blockIdx.x >> 5;

  const int r0 = tid >> 2;
  const int c0 = (tid & 3) * 16;   // k offset (elements) within BK
  const int8_t* Bg0 = WT + (size_t)(bn * BN + r0) * K_DIM + c0;
  const int8_t* Bg1 = Bg0 + (size_t)64 * K_DIM;
  int8_t* Al0 = As + tid * 16;
  int8_t* Al1 = Al0 + 4096;
  int8_t* Bl0 = Bs + tid * 16;
  int8_t* Bl1 = Bl0 + 4096;

  v4i acc[4][4] = {};
  const int8_t* aLds = As + (wm * 64 + l16) * BK + quad * 16;
  const int8_t* bLds = Bs + (wn * 64 + l16) * BK + quad * 16;

  if (i32) {
    const int* Xg0 = (const int*)Xv + (size_t)(bm * BM + r0) * K_DIM + c0;
    const int* Xg1 = Xg0 + (size_t)64 * K_DIM;
    for (int k0 = 0; k0 < K_DIM; k0 += BK) {
      gll16(Bg0 + k0, Bl0);
      gll16(Bg1 + k0, Bl1);
      const int4* p0 = (const int4*)(Xg0 + k0);
      const int4* p1 = (const int4*)(Xg1 + k0);
      uint4 w0, w1;
      w0.x = pack4(p0[0]); w0.y = pack4(p0[1]);
      w0.z = pack4(p0[2]); w0.w = pack4(p0[3]);
      w1.x = pack4(p1[0]); w1.y = pack4(p1[1]);
      w1.z = pack4(p1[2]); w1.w = pack4(p1[3]);
      *(uint4*)Al0 = w0;
      *(uint4*)Al1 = w1;
      __syncthreads();
      v4i af[4], bf[4];
#pragma unroll
      for (int i = 0; i < 4; ++i) af[i] = *(const v4i*)(aLds + i * 16 * BK);
#pragma unroll
      for (int i = 0; i < 4; ++i) bf[i] = *(const v4i*)(bLds + i * 16 * BK);
#pragma unroll
      for (int mi = 0; mi < 4; ++mi)
#pragma unroll
        for (int ni = 0; ni < 4; ++ni)
          acc[mi][ni] = __builtin_amdgcn_mfma_i32_16x16x64_i8(
              af[mi], bf[ni], acc[mi][ni], 0, 0, 0);
      __syncthreads();
    }
  } else {
    const int8_t* Ag0 = (const int8_t*)Xv + (size_t)(bm * BM + r0) * K_DIM + c0;
    const int8_t* Ag1 = Ag0 + (size_t)64 * K_DIM;
    for (int k0 = 0; k0 < K_DIM; k0 += BK) {
      gll16(Ag0 + k0, Al0);
      gll16(Ag1 + k0, Al1);
      gll16(Bg0 + k0, Bl0);
      gll16(Bg1 + k0, Bl1);
      __syncthreads();
      v4i af[4], bf[4];
#pragma unroll
      for (int i = 0; i < 4; ++i) af[i] = *(const v4i*)(aLds + i * 16 * BK);
#pragma unroll
      for (int i = 0; i < 4; ++i) bf[i] = *(const v4i*)(bLds + i * 16 * BK);
#pragma unroll
      for (int mi = 0; mi < 4; ++mi)
#pragma unroll
        for (int ni = 0; ni < 4; ++ni)
          acc[mi][ni] = __builtin_amdgcn_mfma_i32_16x16x64_i8(
              af[mi], bf[ni], acc[mi][ni], 0, 0, 0);
      __syncthreads();
    }
  }
  epilogue(acc, aScale[0], bScale, Y, bm, bn, wm, wn, quad, l16);
}

extern "C" void kernel_launch(void* const* d_in, const int* in_sizes, int n_in,
                              void* d_out, int out_size, void* d_ws,
                              size_t ws_size, hipStream_t stream) {
  const void* Xv = d_in[0];
  const void* Wv = d_in[1];
  const float* a = (const float*)d_in[2];
  const float* b = (const float*)d_in[3];
  int* Y = (int*)d_out;

  const size_t xB = (size_t)M_DIM * K_DIM;  // 32 MB packed X
  const size_t wB = (size_t)N_DIM * K_DIM;  // 16 MB packed W^T

  if (ws_size >= xB + wB + 64) {
    int8_t* Xp = (int8_t*)d_ws;
    int8_t* WT = (int8_t*)d_ws + xB;
    pack_x_f<<<(M_DIM * K_DIM / 4) / 1024, 256, 0, stream>>>(Xv, (u32*)Xp);
    packT_w_f<<<(K_DIM / 64) * (N_DIM / 64), 256, 0, stream>>>(Wv, WT,
                                                               (const int*)Xv);
    gemm_256<<<(M_DIM / 256) * (N_DIM / 256), 512, 0, stream>>>(Xp, WT, a, b,
                                                                Y);
  } else if (ws_size >= wB + 64) {
    int8_t* WT = (int8_t*)d_ws;
    u32* flag = (u32*)((int8_t*)d_ws + wB);
    detect_i32<<<1, 256, 0, stream>>>((const int*)Xv, flag);
    packT_w_f<<<(K_DIM / 64) * (N_DIM / 64), 256, 0, stream>>>(Wv, WT,
                                                               (const int*)Xv);
    gemm_inA<<<(M_DIM / BM) * (N_DIM / BN), 256, 0, stream>>>(Xv, WT, a, b, Y,
                                                              flag);
  } else {
    int8_t* WT = (int8_t*)d_ws;
    u32* flag = (u32*)((int8_t*)d_ws + (ws_size >= wB + 4 ? wB : 0));
    detect_i32<<<1, 256, 0, stream>>>((const int*)Xv, flag);
    packT_w_f<<<(K_DIM / 64) * (N_DIM / 64), 256, 0, stream>>>(Wv, WT,
                                                               (const int*)Xv);
    gemm_inA<<<(M_DIM / BM) * (N_DIM / BN), 256, 0, stream>>>(Xv, WT, a, b, Y,
                                                              flag);
  }
}

// Round 4
// 399.457 us; speedup vs baseline: 1.0970x; 1.0190x over previous
//
#include <hip/hip_runtime.h>
#include <stdint.h>

#define M_DIM 8192   // BATCH*SEQ = 4*2048
#define N_DIM 4096
#define K_DIM 4096
#define BM 128
#define BN 128
#define BK 64

typedef int v4i __attribute__((ext_vector_type(4)));
typedef unsigned u32;

__device__ __forceinline__ void gll16(const void* g, void* l) {
  __builtin_amdgcn_global_load_lds(
      (const __attribute__((address_space(1))) void*)g,
      (__attribute__((address_space(3))) void*)l, 16, 0, 0);
}

__device__ __forceinline__ u32 pack4(const int4 v) {
  return (v.x & 0xffu) | ((v.y & 0xffu) << 8) | ((v.z & 0xffu) << 16) |
         ((u32)(v.w & 0xffu) << 24);
}

// ---------------------------------------------------------------------------
// Header-based dtype detection: first 4 KB of X is in-bounds under both
// hypotheses; i32 materialization iff every word is a sign-extended int8.
// ---------------------------------------------------------------------------
__device__ __forceinline__ bool hdr_is_i32(const int* __restrict__ X, int tid,
                                           int* ok) {
  if (tid == 0) *ok = 1;
  __syncthreads();
  int good = 1;
  for (int i = tid; i < 1024; i += 256) {
    const int w = X[i];
    good &= (w == (int)(int8_t)(w & 0xff));
  }
  if (!good) atomicAnd(ok, 0);
  __syncthreads();
  return *ok != 0;
}

// Standalone detect (fallback paths only; writes flag for gemm_inA).
__global__ __launch_bounds__(256) void detect_i32(const int* __restrict__ X,
                                                  u32* __restrict__ flag) {
  __shared__ int ok;
  const bool i32 = hdr_is_i32(X, threadIdx.x, &ok);
  if (threadIdx.x == 0) *flag = i32 ? 1u : 0u;
}

// ---------------------------------------------------------------------------
// pack_x_f: X -> packed int8 bytes; dtype self-detected from header.
// ---------------------------------------------------------------------------
__global__ __launch_bounds__(256) void pack_x_f(const void* __restrict__ Xin,
                                                u32* __restrict__ out) {
  __shared__ int ok;
  const bool i32 = hdr_is_i32((const int*)Xin, threadIdx.x, &ok);
  const int base = blockIdx.x * 1024 + threadIdx.x;
  if (i32) {
    const int4* in = (const int4*)Xin;  // 128 MB source (valid when int32)
#pragma unroll
    for (int j = 0; j < 4; ++j) {
      const int idx = base + j * 256;
      out[idx] = pack4(in[idx]);
    }
  } else {
    const u32* in = (const u32*)Xin;    // 32 MB source (already bytes)
#pragma unroll
    for (int j = 0; j < 4; ++j) {
      const int idx = base + j * 256;
      out[idx] = in[idx];
    }
  }
}

// ---------------------------------------------------------------------------
// packT_w_f: W [K][N] -> WT int8 [N][K], 64x64 tiles; dtype from X header
// (X and W share the same materialization).
// ---------------------------------------------------------------------------
__global__ __launch_bounds__(256) void packT_w_f(const void* __restrict__ Wv,
                                                 int8_t* __restrict__ WT,
                                                 const int* __restrict__ Xhdr) {
  __shared__ u32 lds[64 * 21];
  __shared__ int ok;
  const int tid = threadIdx.x;
  const bool i32 = hdr_is_i32(Xhdr, tid, &ok);
  const int tk = blockIdx.x & 63;   // k-tile
  const int tn = blockIdx.x >> 6;   // n-tile
  const int k0 = tk * 64, n0 = tn * 64;

#pragma unroll
  for (int j = 0; j < 4; ++j) {
    const int id = j * 256 + tid;
    const int k = id >> 4, c = id & 15;
    u32 word;
    if (i32) {
      const int4 v =
          *(const int4*)((const int*)Wv + (size_t)(k0 + k) * N_DIM + n0 + c * 4);
      word = pack4(v);
    } else {
      word = *(const u32*)((const int8_t*)Wv + (size_t)(k0 + k) * N_DIM + n0 +
                           c * 4);
    }
    lds[k * 21 + c] = word;  // bytes of W[k0+k][n0+c*4 .. +4]
  }
  __syncthreads();
  const int kd = tid & 15, nq = tid >> 4;
  const u32 d0 = lds[(kd * 4 + 0) * 21 + nq];
  const u32 d1 = lds[(kd * 4 + 1) * 21 + nq];
  const u32 d2 = lds[(kd * 4 + 2) * 21 + nq];
  const u32 d3 = lds[(kd * 4 + 3) * 21 + nq];
  u32* outp = (u32*)WT;
#pragma unroll
  for (int i = 0; i < 4; ++i) {
    const u32 e = ((d0 >> (8 * i)) & 0xffu) | (((d1 >> (8 * i)) & 0xffu) << 8) |
                  (((d2 >> (8 * i)) & 0xffu) << 16) |
                  (((d3 >> (8 * i)) & 0xffu) << 24);
    const int n = n0 + nq * 4 + i;
    outp[(size_t)n * (K_DIM / 4) + (k0 / 4) + kd] = e;
  }
}

// ---------------------------------------------------------------------------
// epilogue (128² fallback): C/D layout col = lane&15, row = quad*4 + reg.
// ---------------------------------------------------------------------------
__device__ __forceinline__ void epilogue(const v4i acc[4][4], float a,
                                         const float* __restrict__ bScale,
                                         int* __restrict__ Y, int bm, int bn,
                                         int wm, int wn, int quad, int l16) {
  const int nBase = bn * BN + wn * 64 + l16;
  float bs[4];
#pragma unroll
  for (int ni = 0; ni < 4; ++ni) bs[ni] = bScale[nBase + ni * 16];
#pragma unroll
  for (int mi = 0; mi < 4; ++mi) {
    const int m0 = bm * BM + wm * 64 + mi * 16 + quad * 4;
#pragma unroll
    for (int r = 0; r < 4; ++r) {
      int* row = Y + (size_t)(m0 + r) * N_DIM + nBase;
#pragma unroll
      for (int ni = 0; ni < 4; ++ni) {
        float v = ((float)acc[mi][ni][r] * a) * bs[ni];
        v = rintf(v);
        v = fminf(fmaxf(v, -128.f), 127.f);
        row[ni * 16] = (int)v;
      }
    }
  }
}

// ---- gemm_256 helpers -----------------------------------------------------
__device__ __forceinline__ void rd4(v4i* f, const int8_t* base, int off) {
#pragma unroll
  for (int i = 0; i < 4; ++i) f[i] = *(const v4i*)(base + off + i * 1024);
}

__device__ __forceinline__ void mfma16(v4i acc[8][4], int row, const v4i* a,
                                       const v4i* b) {
#pragma unroll
  for (int mi = 0; mi < 4; ++mi)
#pragma unroll
    for (int ni = 0; ni < 4; ++ni)
      acc[row + mi][ni] = __builtin_amdgcn_mfma_i32_16x16x64_i8(
          a[mi], b[ni], acc[row + mi][ni], 0, 0, 0);
}

// One kstep with register-double-buffered fragments:
//   P = fragments for THIS kstep (already in regs),
//   Q = fragments for kstep g+1, prefetched here, consumed next kstep.
__device__ __forceinline__ void kstep(
    int g, const int8_t* xa, const int8_t* xb, int8_t* ldsA, int8_t* ldsB,
    const int8_t* aBase, const int8_t* bBase, v4i afP[4], v4i bfP[4],
    v4i afQ[4], v4i bfQ[4], v4i acc[8][4]) {
  const int soff = (g & 3) << 14;
  // stage kstep g+3 (slot (g+3)&3 == (g-1)&3: ring-safe, see barrier note)
  if (g <= 60) {
    const int poff = ((g + 3) & 3) << 14;
    const int8_t* sa = xa + (size_t)(g + 3) * 64;
    const int8_t* sb = xb + (size_t)(g + 3) * 64;
    gll16(sa, ldsA + poff);
    gll16(sa + (size_t)128 * K_DIM, ldsA + poff + 8192);
    gll16(sb, ldsB + poff);
    gll16(sb + (size_t)128 * K_DIM, ldsB + poff + 8192);
  }
  // prefetch next kstep's af/bf; slot g+1 retired by vmcnt(4) at end of g-1
  if (g <= 62) {
    const int qoff = ((g + 1) & 3) << 14;
    rd4(bfQ, bBase, qoff);
    rd4(afQ, aBase, qoff);
  }
  // pin the prefetch above the MFMA cluster (no sinking across)
  __builtin_amdgcn_sched_barrier(0);
  __builtin_amdgcn_s_setprio(1);
  mfma16(acc, 0, afP, bfP);
  v4i ag[4];
  rd4(ag, aBase, soff + 4096);  // current kstep second-half A: hides under
  mfma16(acc, 4, ag, bfP);      // the first 16 MFMAs
  __builtin_amdgcn_s_setprio(0);
  // counted retire: slots g+1 AND g+2 resident after this wait (prefetch
  // reads slot g+1 next kstep); only slot g+3's 4 loads stay in flight.
  if (g <= 60)
    asm volatile("s_waitcnt vmcnt(4)" ::: "memory");
  else if (g == 61)
    asm volatile("s_waitcnt vmcnt(0)" ::: "memory");
  if (g <= 61) __builtin_amdgcn_s_barrier();
}

// ---------------------------------------------------------------------------
// gemm_256: 256x256 tile, 8 waves (2M x 4N), mfma_i32_16x16x64_i8
// (HW-verified conflict-free fragment layout), one barrier per kstep,
// register-double-buffered fragments (af/bf P<->Q, unroll x2):
//  - K as 64 ksteps of 64 B; LDS ring of 4 kstep-slots/operand (128 KB).
//  - prefetch distance 3 on the DMA ring; counted vmcnt(4) per kstep.
//  - fragment prefetch of kstep g+1 issues BEFORE kstep g's MFMA cluster;
//    its LDS latency hides under ~650 cyc of MFMA issue (this was the
//    serialized ~1100 cyc/kstep R1/R3 left exposed).
//  - T2 XOR swizzle via pre-swizzled global source + swizzled ds_read.
//  - T5 setprio; T1 bijective XCD swizzle (512%8==0).
// ---------------------------------------------------------------------------
__global__ __launch_bounds__(512, 2) void gemm_256(
    const int8_t* __restrict__ X, const int8_t* __restrict__ WT,
    const float* __restrict__ aScale, const float* __restrict__ bScale,
    int* __restrict__ Y) {
  __shared__ __align__(16) int8_t lds[131072];  // A ring 64KB | B ring 64KB
  const int tid = threadIdx.x;
  const int lane = tid & 63;
  const int wave = tid >> 6;
  const int quad = lane >> 4, l16 = lane & 15;
  const int wm = wave >> 2, wn = wave & 3;  // 2 x 4 wave grid

  // XCD-aware bijective swizzle: nwg=512, 64 blocks/XCD
  const int swzb = (blockIdx.x & 7) * 64 + (blockIdx.x >> 3);
  const int bn = swzb & 15, bm = swzb >> 4;  // bn inner: A-panel reuse per XCD

  // write-side swizzle selector: row = tid>>2  ->  (row>>1)&3 = (tid>>3)&3
  const int clog = (((tid & 3) ^ ((tid >> 3) & 3)) << 4);
  // read-side: row = {wm*128|wn*64} + {mi|ni}*16 + l16 -> (row>>1)&3 = (l16>>1)&3
  const int pc = quad ^ ((l16 >> 1) & 3);

  const int8_t* xa = X + (size_t)(bm * 256 + (tid >> 2)) * K_DIM + clog;
  const int8_t* xb = WT + (size_t)(bn * 256 + (tid >> 2)) * K_DIM + clog;
  int8_t* ldsA = lds + tid * 16;           // linear DMA dest, round1 at +8192
  int8_t* ldsB = lds + 65536 + tid * 16;
  const int8_t* aBase = lds + (wm * 128 + l16) * 64 + pc * 16;
  const int8_t* bBase = lds + 65536 + (wn * 64 + l16) * 64 + pc * 16;

  v4i acc[8][4] = {};

  // prologue: stage ksteps 0..2 (per kstep: A r0, A r1, B r0, B r1)
#pragma unroll
  for (int t = 0; t < 3; ++t) {
    gll16(xa + t * 64, ldsA + t * 16384);
    gll16(xa + (size_t)128 * K_DIM + t * 64, ldsA + t * 16384 + 8192);
    gll16(xb + t * 64, ldsB + t * 16384);
    gll16(xb + (size_t)128 * K_DIM + t * 64, ldsB + t * 16384 + 8192);
  }
  // slots 0 AND 1 landed (kstep 0 reads slot 0 as cur + slot 1 as prefetch)
  asm volatile("s_waitcnt vmcnt(4)" ::: "memory");
  __builtin_amdgcn_s_barrier();

  v4i afP[4], bfP[4], afQ[4], bfQ[4];
  rd4(bfP, bBase, 0);
  rd4(afP, aBase, 0);

  for (int g = 0; g < 64; g += 2) {
    kstep(g, xa, xb, ldsA, ldsB, aBase, bBase, afP, bfP, afQ, bfQ, acc);
    kstep(g + 1, xa, xb, ldsA, ldsB, aBase, bBase, afQ, bfQ, afP, bfP, acc);
  }

  // ---- epilogue: col = lane&15, row = quad*4 + reg ----
  const float a = aScale[0];
  const int nBase = bn * 256 + wn * 64 + l16;
  float bs[4];
#pragma unroll
  for (int ni = 0; ni < 4; ++ni) bs[ni] = bScale[nBase + ni * 16];
#pragma unroll
  for (int mi = 0; mi < 8; ++mi) {
    const int m0 = bm * 256 + wm * 128 + mi * 16 + quad * 4;
#pragma unroll
    for (int r = 0; r < 4; ++r) {
      int* row = Y + (size_t)(m0 + r) * N_DIM + nBase;
#pragma unroll
      for (int ni = 0; ni < 4; ++ni) {
        float v = ((float)acc[mi][ni][r] * a) * bs[ni];
        v = rintf(v);
        v = fminf(fmaxf(v, -128.f), 127.f);
        row[ni * 16] = (int)v;
      }
    }
  }
}

// ---------------------------------------------------------------------------
// gemm_inA (fallback when ws only fits WT): A read from X (dtype by flag,
// packed in-kernel), B from packed WT. GEMM never writes ws -> no race.
// ---------------------------------------------------------------------------
__global__ __launch_bounds__(256) void gemm_inA(
    const void* __restrict__ Xv, const int8_t* __restrict__ WT,
    const float* __restrict__ aScale, const float* __restrict__ bScale,
    int* __restrict__ Y, const u32* __restrict__ flag) {
  __shared__ __align__(16) int8_t As[BM * BK];
  __shared__ __align__(16) int8_t Bs[BN * BK];
  const bool i32 = (*flag != 0);
  const int tid = threadIdx.x;
  const int lane = tid & 63, wave = tid >> 6;
  const int quad = lane >> 4, l16 = lane & 15;
  const int wm = wave & 1, wn = wave >> 1;
  const int bn = blockIdx.x & 31;
  const int bm = blockIdx.x >> 5;

  const int r0 = tid >> 2;
  const int c0 = (tid & 3) * 16;   // k offset (elements) within BK
  const int8_t* Bg0 = WT + (size_t)(bn * BN + r0) * K_DIM + c0;
  const int8_t* Bg1 = Bg0 + (size_t)64 * K_DIM;
  int8_t* Al0 = As + tid * 16;
  int8_t* Al1 = Al0 + 4096;
  int8_t* Bl0 = Bs + tid * 16;
  int8_t* Bl1 = Bl0 + 4096;

  v4i acc[4][4] = {};
  const int8_t* aLds = As + (wm * 64 + l16) * BK + quad * 16;
  const int8_t* bLds = Bs + (wn * 64 + l16) * BK + quad * 16;

  if (i32) {
    const int* Xg0 = (const int*)Xv + (size_t)(bm * BM + r0) * K_DIM + c0;
    const int* Xg1 = Xg0 + (size_t)64 * K_DIM;
    for (int k0 = 0; k0 < K_DIM; k0 += BK) {
      gll16(Bg0 + k0, Bl0);
      gll16(Bg1 + k0, Bl1);
      const int4* p0 = (const int4*)(Xg0 + k0);
      const int4* p1 = (const int4*)(Xg1 + k0);
      uint4 w0, w1;
      w0.x = pack4(p0[0]); w0.y = pack4(p0[1]);
      w0.z = pack4(p0[2]); w0.w = pack4(p0[3]);
      w1.x = pack4(p1[0]); w1.y = pack4(p1[1]);
      w1.z = pack4(p1[2]); w1.w = pack4(p1[3]);
      *(uint4*)Al0 = w0;
      *(uint4*)Al1 = w1;
      __syncthreads();
      v4i af[4], bf[4];
#pragma unroll
      for (int i = 0; i < 4; ++i) af[i] = *(const v4i*)(aLds + i * 16 * BK);
#pragma unroll
      for (int i = 0; i < 4; ++i) bf[i] = *(const v4i*)(bLds + i * 16 * BK);
#pragma unroll
      for (int mi = 0; mi < 4; ++mi)
#pragma unroll
        for (int ni = 0; ni < 4; ++ni)
          acc[mi][ni] = __builtin_amdgcn_mfma_i32_16x16x64_i8(
              af[mi], bf[ni], acc[mi][ni], 0, 0, 0);
      __syncthreads();
    }
  } else {
    const int8_t* Ag0 = (const int8_t*)Xv + (size_t)(bm * BM + r0) * K_DIM + c0;
    const int8_t* Ag1 = Ag0 + (size_t)64 * K_DIM;
    for (int k0 = 0; k0 < K_DIM; k0 += BK) {
      gll16(Ag0 + k0, Al0);
      gll16(Ag1 + k0, Al1);
      gll16(Bg0 + k0, Bl0);
      gll16(Bg1 + k0, Bl1);
      __syncthreads();
      v4i af[4], bf[4];
#pragma unroll
      for (int i = 0; i < 4; ++i) af[i] = *(const v4i*)(aLds + i * 16 * BK);
#pragma unroll
      for (int i = 0; i < 4; ++i) bf[i] = *(const v4i*)(bLds + i * 16 * BK);
#pragma unroll
      for (int mi = 0; mi < 4; ++mi)
#pragma unroll
        for (int ni = 0; ni < 4; ++ni)
          acc[mi][ni] = __builtin_amdgcn_mfma_i32_16x16x64_i8(
              af[mi], bf[ni], acc[mi][ni], 0, 0, 0);
      __syncthreads();
    }
  }
  epilogue(acc, aScale[0], bScale, Y, bm, bn, wm, wn, quad, l16);
}

extern "C" void kernel_launch(void* const* d_in, const int* in_sizes, int n_in,
                              void* d_out, int out_size, void* d_ws,
                              size_t ws_size, hipStream_t stream) {
  const void* Xv = d_in[0];
  const void* Wv = d_in[1];
  const float* a = (const float*)d_in[2];
  const float* b = (const float*)d_in[3];
  int* Y = (int*)d_out;

  const size_t xB = (size_t)M_DIM * K_DIM;  // 32 MB packed X
  const size_t wB = (size_t)N_DIM * K_DIM;  // 16 MB packed W^T

  if (ws_size >= xB + wB + 64) {
    int8_t* Xp = (int8_t*)d_ws;
    int8_t* WT = (int8_t*)d_ws + xB;
    pack_x_f<<<(M_DIM * K_DIM / 4) / 1024, 256, 0, stream>>>(Xv, (u32*)Xp);
    packT_w_f<<<(K_DIM / 64) * (N_DIM / 64), 256, 0, stream>>>(Wv, WT,
                                                               (const int*)Xv);
    gemm_256<<<(M_DIM / 256) * (N_DIM / 256), 512, 0, stream>>>(Xp, WT, a, b,
                                                                Y);
  } else if (ws_size >= wB + 64) {
    int8_t* WT = (int8_t*)d_ws;
    u32* flag = (u32*)((int8_t*)d_ws + wB);
    detect_i32<<<1, 256, 0, stream>>>((const int*)Xv, flag);
    packT_w_f<<<(K_DIM / 64) * (N_DIM / 64), 256, 0, stream>>>(Wv, WT,
                                                               (const int*)Xv);
    gemm_inA<<<(M_DIM / BM) * (N_DIM / BN), 256, 0, stream>>>(Xv, WT, a, b, Y,
                                                              flag);
  } else {
    int8_t* WT = (int8_t*)d_ws;
    u32* flag = (u32*)((int8_t*)d_ws + (ws_size >= wB + 4 ? wB : 0));
    detect_i32<<<1, 256, 0, stream>>>((const int*)Xv, flag);
    packT_w_f<<<(K_DIM / 64) * (N_DIM / 64), 256, 0, stream>>>(Wv, WT,
                                                               (const int*)Xv);
    gemm_inA<<<(M_DIM / BM) * (N_DIM / BN), 256, 0, stream>>>(Xv, WT, a, b, Y,
                                                              flag);
  }
}